// Round 1
// baseline (2172.511 us; speedup 1.0000x reference)
//
#include <hip/hip_runtime.h>
#include <hip/hip_bf16.h>

// SGC: out = A^2 x W + b, A = D^-1/2 (adj) D^-1/2 built from edge_index,
// deg counted over col (destination), messages scattered to col.

#define N_NODES 100000
#define N_EDGES 1600000
#define IN_CH 48
#define OUT_CH 64

// ---- degree count over col ----
__global__ void degree_kernel(const int* __restrict__ col, float* __restrict__ deg, int n_edges) {
    int e = blockIdx.x * blockDim.x + threadIdx.x;
    if (e < n_edges) {
        atomicAdd(&deg[col[e]], 1.0f);
    }
}

// ---- in-place deg -> deg_inv_sqrt ----
__global__ void invsqrt_kernel(float* __restrict__ deg, int n) {
    int i = blockIdx.x * blockDim.x + threadIdx.x;
    if (i < n) {
        float d = deg[i];
        deg[i] = (d > 0.0f) ? rsqrtf(d) : 0.0f;
    }
}

// ---- one propagation round: h_out[col] += h_in[row] * dis[row]*dis[col] ----
// 12 threads per edge, each handles one float4 (4 channels) of the 48-ch row.
__global__ void propagate_kernel(const float* __restrict__ h_in,
                                 const int* __restrict__ row,
                                 const int* __restrict__ col,
                                 const float* __restrict__ dis,
                                 float* __restrict__ h_out,
                                 int n_edges) {
    int t = blockIdx.x * blockDim.x + threadIdx.x;
    int e = t / 12;
    int c = t % 12;
    if (e >= n_edges) return;
    int r = row[e];
    int d = col[e];
    float norm = dis[r] * dis[d];
    const float4* src = (const float4*)(h_in + (size_t)r * IN_CH);
    float4 v = src[c];
    float* dst = h_out + (size_t)d * IN_CH + c * 4;
    atomicAdd(dst + 0, v.x * norm);
    atomicAdd(dst + 1, v.y * norm);
    atomicAdd(dst + 2, v.z * norm);
    atomicAdd(dst + 3, v.w * norm);
}

// ---- final: out[i,j] = sum_k h[i,k] * W[k,j] + b[j]  (48x64) ----
// 256 threads/block = 4 rows; W (12 KB), b, and the 4 rows staged in LDS.
__global__ void gemm_kernel(const float* __restrict__ h,
                            const float* __restrict__ W,
                            const float* __restrict__ b,
                            float* __restrict__ out,
                            int n) {
    __shared__ float sW[IN_CH * OUT_CH];
    __shared__ float sb[OUT_CH];
    __shared__ float srow[4 * IN_CH];

    for (int i = threadIdx.x; i < IN_CH * OUT_CH; i += blockDim.x) sW[i] = W[i];
    if (threadIdx.x < OUT_CH) sb[threadIdx.x] = b[threadIdx.x];

    int r0 = blockIdx.x * 4;
    if (threadIdx.x < 4 * IN_CH) {
        int rr = r0 * IN_CH + threadIdx.x;
        srow[threadIdx.x] = h[rr];
    }
    __syncthreads();

    int local = threadIdx.x >> 6;       // 0..3
    int j = threadIdx.x & 63;           // 0..63
    int i = r0 + local;
    if (i >= n) return;

    float acc = sb[j];
    #pragma unroll
    for (int k = 0; k < IN_CH; k++) {
        acc += srow[local * IN_CH + k] * sW[k * OUT_CH + j];
    }
    out[(size_t)i * OUT_CH + j] = acc;
}

extern "C" void kernel_launch(void* const* d_in, const int* in_sizes, int n_in,
                              void* d_out, int out_size, void* d_ws, size_t ws_size,
                              hipStream_t stream) {
    const float* x   = (const float*)d_in[0];
    const int*   ei  = (const int*)d_in[1];
    const float* W   = (const float*)d_in[2];
    const float* b   = (const float*)d_in[3];
    float* out = (float*)d_out;

    const int* row = ei;             // edge_index[0]
    const int* col = ei + N_EDGES;   // edge_index[1]

    float* ws  = (float*)d_ws;
    float* dis = ws;                       // N_NODES floats (deg, then in-place inv-sqrt)
    float* h1  = ws + 100352;              // 256B-aligned
    float* h2  = h1 + (size_t)N_NODES * IN_CH;

    hipMemsetAsync(dis, 0, (size_t)N_NODES * sizeof(float), stream);
    hipMemsetAsync(h1, 0, (size_t)N_NODES * IN_CH * sizeof(float), stream);
    hipMemsetAsync(h2, 0, (size_t)N_NODES * IN_CH * sizeof(float), stream);

    degree_kernel<<<(N_EDGES + 255) / 256, 256, 0, stream>>>(col, dis, N_EDGES);
    invsqrt_kernel<<<(N_NODES + 255) / 256, 256, 0, stream>>>(dis, N_NODES);

    int prop_threads = N_EDGES * 12;
    int prop_blocks = (prop_threads + 255) / 256;
    propagate_kernel<<<prop_blocks, 256, 0, stream>>>(x,  row, col, dis, h1, N_EDGES);
    propagate_kernel<<<prop_blocks, 256, 0, stream>>>(h1, row, col, dis, h2, N_EDGES);

    gemm_kernel<<<(N_NODES + 3) / 4, 256, 0, stream>>>(h2, W, b, out, N_NODES);
}

// Round 2
// 447.219 us; speedup vs baseline: 4.8578x; 4.8578x over previous
//
#include <hip/hip_runtime.h>
#include <hip/hip_bf16.h>

// SGC: out = (D^-1/2 A D^-1/2)^2 x W + b.
// R1 strategy: build CSR-by-destination per launch (int atomics), then
// gather-based propagation (no fp32 atomics, one write per node per round).
// Scale folding: round1 gathers x[src]*dis[src], post-scales by dis[i]^2
// (pre-scales round-2 input); round2 gathers raw, post-scales by dis[i].
// h1 lives in d_out (25.6 MB, dead before final GEMM overwrites it).

#define N_NODES 100000
#define N_EDGES 1600000
#define IN_CH 48
#define OUT_CH 64

// ---- integer degree histogram over col ----
__global__ void degree_kernel(const int* __restrict__ col, int* __restrict__ deg, int n_edges) {
    int e = blockIdx.x * blockDim.x + threadIdx.x;
    if (e < n_edges) atomicAdd(&deg[col[e]], 1);
}

// ---- block-aggregated exclusive scan -> start/cursor; also dis = rsqrt(deg) ----
// Block ranges are assigned via one atomic per block (unordered base is fine:
// we only need disjoint contiguous ranges per node, not sorted ranges).
__global__ void scan_kernel(const int* __restrict__ deg,
                            int* __restrict__ start, int* __restrict__ cursor,
                            float* __restrict__ dis, int* __restrict__ counter, int n) {
    __shared__ int waveSum[4];
    __shared__ int waveOff[4];
    __shared__ int blockBase;
    int i = blockIdx.x * 256 + threadIdx.x;
    int lane = threadIdx.x & 63;
    int w = threadIdx.x >> 6;
    int d = (i < n) ? deg[i] : 0;
    int incl = d;
    #pragma unroll
    for (int o = 1; o < 64; o <<= 1) {
        int v = __shfl_up(incl, o, 64);
        if (lane >= o) incl += v;
    }
    if (lane == 63) waveSum[w] = incl;
    __syncthreads();
    if (threadIdx.x == 0) {
        int t = 0;
        for (int k = 0; k < 4; k++) { waveOff[k] = t; t += waveSum[k]; }
        blockBase = atomicAdd(counter, t);
    }
    __syncthreads();
    if (i < n) {
        int st = blockBase + waveOff[w] + incl - d;
        start[i] = st;
        cursor[i] = st;
        dis[i] = (d > 0) ? rsqrtf((float)d) : 0.0f;
    }
}

// ---- scatter edges into CSR slots ----
__global__ void fill_kernel(const int* __restrict__ row, const int* __restrict__ col,
                            int* __restrict__ cursor, int* __restrict__ edge_src, int n_edges) {
    int e = blockIdx.x * blockDim.x + threadIdx.x;
    if (e < n_edges) {
        int p = atomicAdd(&cursor[col[e]], 1);
        edge_src[p] = row[e];
    }
}

// ---- gather propagation: 16 lanes per node, 3 channels per lane ----
// ROUND==1: acc += h_in[src]*dis[src]; out = acc*dis[i]^2  (pre-scales next round)
// ROUND==2: acc += h_in[src];          out = acc*dis[i]
template<int ROUND>
__global__ void gather_kernel(const float* __restrict__ h_in,
                              const int* __restrict__ start,
                              const int* __restrict__ endp,
                              const int* __restrict__ edge_src,
                              const float* __restrict__ dis,
                              float* __restrict__ h_out) {
    int node = blockIdx.x * 16 + (threadIdx.x >> 4);
    int lane = threadIdx.x & 15;
    float a0 = 0.0f, a1 = 0.0f, a2 = 0.0f;
    int s = start[node], e = endp[node];
    for (int j = s; j < e; ++j) {
        int src = edge_src[j];
        const float* p = h_in + (size_t)src * IN_CH + lane;
        if (ROUND == 1) {
            float ds = dis[src];
            a0 += p[0] * ds; a1 += p[16] * ds; a2 += p[32] * ds;
        } else {
            a0 += p[0]; a1 += p[16]; a2 += p[32];
        }
    }
    float sc = (ROUND == 1) ? dis[node] * dis[node] : dis[node];
    float* q = h_out + (size_t)node * IN_CH + lane;
    q[0] = a0 * sc; q[16] = a1 * sc; q[32] = a2 * sc;
}

// ---- final: out[i,j] = sum_k h[i,k] * W[k,j] + b[j]  (48x64) ----
__global__ void gemm_kernel(const float* __restrict__ h,
                            const float* __restrict__ W,
                            const float* __restrict__ b,
                            float* __restrict__ out,
                            int n) {
    __shared__ float sW[IN_CH * OUT_CH];
    __shared__ float sb[OUT_CH];
    __shared__ float srow[4 * IN_CH];

    for (int i = threadIdx.x; i < IN_CH * OUT_CH; i += blockDim.x) sW[i] = W[i];
    if (threadIdx.x < OUT_CH) sb[threadIdx.x] = b[threadIdx.x];

    int r0 = blockIdx.x * 4;
    if (threadIdx.x < 4 * IN_CH) srow[threadIdx.x] = h[(size_t)r0 * IN_CH + threadIdx.x];
    __syncthreads();

    int local = threadIdx.x >> 6;
    int j = threadIdx.x & 63;
    int i = r0 + local;
    if (i >= n) return;

    float acc = sb[j];
    #pragma unroll
    for (int k = 0; k < IN_CH; k++) acc += srow[local * IN_CH + k] * sW[k * OUT_CH + j];
    out[(size_t)i * OUT_CH + j] = acc;
}

extern "C" void kernel_launch(void* const* d_in, const int* in_sizes, int n_in,
                              void* d_out, int out_size, void* d_ws, size_t ws_size,
                              hipStream_t stream) {
    const float* x   = (const float*)d_in[0];
    const int*   ei  = (const int*)d_in[1];
    const float* W   = (const float*)d_in[2];
    const float* b   = (const float*)d_in[3];
    float* out = (float*)d_out;

    const int* row = ei;             // edge_index[0] (sources)
    const int* col = ei + N_EDGES;   // edge_index[1] (destinations)

    // ws layout (all 4-byte elements), total ~27.2 MB:
    int* ws_i = (int*)d_ws;
    int* deg      = ws_i;                    // [100000] + counter at +100000, pad to 100352
    int* counter  = ws_i + 100000;           // [1]
    int* start    = ws_i + 100352;           // [100000] pad 100352
    int* cursor   = start + 100352;          // [100000] pad 100352 (becomes end after fill)
    float* dis    = (float*)(cursor + 100352); // [100000] pad 100352
    int* edge_src = (int*)(dis + 100352);    // [1600000]
    float* h2     = (float*)(edge_src + N_EDGES); // [4800000]
    float* h1     = out;                     // d_out as scratch (fully rewritten by gemm)

    hipMemsetAsync(deg, 0, 100352 * sizeof(int), stream);  // deg + counter

    degree_kernel<<<(N_EDGES + 255) / 256, 256, 0, stream>>>(col, deg, N_EDGES);
    scan_kernel<<<(N_NODES + 255) / 256, 256, 0, stream>>>(deg, start, cursor, dis, counter, N_NODES);
    fill_kernel<<<(N_EDGES + 255) / 256, 256, 0, stream>>>(row, col, cursor, edge_src, N_EDGES);

    // 16 nodes per 256-thread block; 100000/16 = 6250 exactly
    gather_kernel<1><<<N_NODES / 16, 256, 0, stream>>>(x,  start, cursor, edge_src, dis, h1);
    gather_kernel<2><<<N_NODES / 16, 256, 0, stream>>>(h1, start, cursor, edge_src, dis, h2);

    gemm_kernel<<<N_NODES / 4, 256, 0, stream>>>(h2, W, b, out, N_NODES);
}

// Round 3
// 351.174 us; speedup vs baseline: 6.1864x; 1.2735x over previous
//
#include <hip/hip_runtime.h>
#include <hip/hip_bf16.h>

// SGC: out = (D^-1/2 A D^-1/2)^2 x W + b.
// R2: fuse rank assignment into the degree histogram (atomicAdd return value),
// making the CSR scatter atomic-free (pure stores). Drops cursor array.
// Gather rounds + GEMM unchanged from R1.

#define N_NODES 100000
#define N_EDGES 1600000
#define IN_CH 48
#define OUT_CH 64

// ---- degree histogram over col; side-output: per-edge rank within node ----
__global__ void degree_rank_kernel(const int* __restrict__ col, int* __restrict__ deg,
                                   int* __restrict__ rank, int n_edges) {
    int e = blockIdx.x * blockDim.x + threadIdx.x;
    if (e < n_edges) {
        rank[e] = atomicAdd(&deg[col[e]], 1);
    }
}

// ---- block-aggregated exclusive scan -> start; also dis = rsqrt(deg) ----
// Block base offsets via one atomic per block (unordered base is fine: we only
// need disjoint contiguous per-node ranges, not globally sorted ranges).
__global__ void scan_kernel(const int* __restrict__ deg,
                            int* __restrict__ start,
                            float* __restrict__ dis, int* __restrict__ counter, int n) {
    __shared__ int waveSum[4];
    __shared__ int waveOff[4];
    __shared__ int blockBase;
    int i = blockIdx.x * 256 + threadIdx.x;
    int lane = threadIdx.x & 63;
    int w = threadIdx.x >> 6;
    int d = (i < n) ? deg[i] : 0;
    int incl = d;
    #pragma unroll
    for (int o = 1; o < 64; o <<= 1) {
        int v = __shfl_up(incl, o, 64);
        if (lane >= o) incl += v;
    }
    if (lane == 63) waveSum[w] = incl;
    __syncthreads();
    if (threadIdx.x == 0) {
        int t = 0;
        for (int k = 0; k < 4; k++) { waveOff[k] = t; t += waveSum[k]; }
        blockBase = atomicAdd(counter, t);
    }
    __syncthreads();
    if (i < n) {
        start[i] = blockBase + waveOff[w] + incl - d;
        dis[i] = (d > 0) ? rsqrtf((float)d) : 0.0f;
    }
}

// ---- atomic-free CSR scatter: slot = start[col[e]] + rank[e] ----
__global__ void scatter_kernel(const int* __restrict__ row, const int* __restrict__ col,
                               const int* __restrict__ start, const int* __restrict__ rank,
                               int* __restrict__ edge_src, int n_edges) {
    int e = blockIdx.x * blockDim.x + threadIdx.x;
    if (e < n_edges) {
        edge_src[start[col[e]] + rank[e]] = row[e];
    }
}

// ---- gather propagation: 16 lanes per node, 3 channels per lane ----
// ROUND==1: acc += h_in[src]*dis[src]; out = acc*dis[i]^2  (pre-scales next round)
// ROUND==2: acc += h_in[src];          out = acc*dis[i]
template<int ROUND>
__global__ void gather_kernel(const float* __restrict__ h_in,
                              const int* __restrict__ start,
                              const int* __restrict__ deg,
                              const int* __restrict__ edge_src,
                              const float* __restrict__ dis,
                              float* __restrict__ h_out) {
    int node = blockIdx.x * 16 + (threadIdx.x >> 4);
    int lane = threadIdx.x & 15;
    float a0 = 0.0f, a1 = 0.0f, a2 = 0.0f;
    int s = start[node];
    int e = s + deg[node];
    for (int j = s; j < e; ++j) {
        int src = edge_src[j];
        const float* p = h_in + (size_t)src * IN_CH + lane;
        if (ROUND == 1) {
            float ds = dis[src];
            a0 += p[0] * ds; a1 += p[16] * ds; a2 += p[32] * ds;
        } else {
            a0 += p[0]; a1 += p[16]; a2 += p[32];
        }
    }
    float sc = (ROUND == 1) ? dis[node] * dis[node] : dis[node];
    float* q = h_out + (size_t)node * IN_CH + lane;
    q[0] = a0 * sc; q[16] = a1 * sc; q[32] = a2 * sc;
}

// ---- final: out[i,j] = sum_k h[i,k] * W[k,j] + b[j]  (48x64) ----
__global__ void gemm_kernel(const float* __restrict__ h,
                            const float* __restrict__ W,
                            const float* __restrict__ b,
                            float* __restrict__ out,
                            int n) {
    __shared__ float sW[IN_CH * OUT_CH];
    __shared__ float sb[OUT_CH];
    __shared__ float srow[4 * IN_CH];

    for (int i = threadIdx.x; i < IN_CH * OUT_CH; i += blockDim.x) sW[i] = W[i];
    if (threadIdx.x < OUT_CH) sb[threadIdx.x] = b[threadIdx.x];

    int r0 = blockIdx.x * 4;
    if (threadIdx.x < 4 * IN_CH) srow[threadIdx.x] = h[(size_t)r0 * IN_CH + threadIdx.x];
    __syncthreads();

    int local = threadIdx.x >> 6;
    int j = threadIdx.x & 63;
    int i = r0 + local;
    if (i >= n) return;

    float acc = sb[j];
    #pragma unroll
    for (int k = 0; k < IN_CH; k++) acc += srow[local * IN_CH + k] * sW[k * OUT_CH + j];
    out[(size_t)i * OUT_CH + j] = acc;
}

extern "C" void kernel_launch(void* const* d_in, const int* in_sizes, int n_in,
                              void* d_out, int out_size, void* d_ws, size_t ws_size,
                              hipStream_t stream) {
    const float* x   = (const float*)d_in[0];
    const int*   ei  = (const int*)d_in[1];
    const float* W   = (const float*)d_in[2];
    const float* b   = (const float*)d_in[3];
    float* out = (float*)d_out;

    const int* row = ei;             // edge_index[0] (sources)
    const int* col = ei + N_EDGES;   // edge_index[1] (destinations)

    // ws layout (4-byte elems), ~33.2 MB total:
    int* ws_i = (int*)d_ws;
    int* deg      = ws_i;                       // [100000], counter at +100000, pad 100352
    int* counter  = ws_i + 100000;              // [1]
    int* start    = ws_i + 100352;              // [100000] pad 100352
    float* dis    = (float*)(start + 100352);   // [100000] pad 100352
    int* rank     = (int*)(dis + 100352);       // [1600000]
    int* edge_src = rank + N_EDGES;             // [1600000]
    float* h2     = (float*)(edge_src + N_EDGES); // [4800000]
    float* h1     = out;                        // d_out as scratch (dead before gemm)

    hipMemsetAsync(deg, 0, 100352 * sizeof(int), stream);  // deg + counter

    degree_rank_kernel<<<(N_EDGES + 255) / 256, 256, 0, stream>>>(col, deg, rank, N_EDGES);
    scan_kernel<<<(N_NODES + 255) / 256, 256, 0, stream>>>(deg, start, dis, counter, N_NODES);
    scatter_kernel<<<(N_EDGES + 255) / 256, 256, 0, stream>>>(row, col, start, rank, edge_src, N_EDGES);

    // 16 nodes per 256-thread block; 100000/16 = 6250 exactly
    gather_kernel<1><<<N_NODES / 16, 256, 0, stream>>>(x,  start, deg, edge_src, dis, h1);
    gather_kernel<2><<<N_NODES / 16, 256, 0, stream>>>(h1, start, deg, edge_src, dis, h2);

    gemm_kernel<<<N_NODES / 4, 256, 0, stream>>>(h2, W, b, out, N_NODES);
}

// Round 4
// 293.678 us; speedup vs baseline: 7.3976x; 1.1958x over previous
//
#include <hip/hip_runtime.h>
#include <hip/hip_bf16.h>
#include <hip/hip_fp16.h>

// SGC: out = (D^-1/2 A D^-1/2)^2 x W + b.
// R3: (a) fp16 staging of gather sources (xs = x*dis, h1) -> half the random
// fetch bytes + better per-XCD L2 hit rate; fp32 accumulation throughout.
// (b) GEMM fused into gather round 2 (h2 never materialized).
// CSR build (degree_rank / scan / scatter) unchanged from R2.

#define N_NODES 100000
#define N_EDGES 1600000
#define IN_CH 48
#define OUT_CH 64

// ---- degree histogram over col; side-output: per-edge rank within node ----
__global__ void degree_rank_kernel(const int* __restrict__ col, int* __restrict__ deg,
                                   int* __restrict__ rank, int n_edges) {
    int e = blockIdx.x * blockDim.x + threadIdx.x;
    if (e < n_edges) {
        rank[e] = atomicAdd(&deg[col[e]], 1);
    }
}

// ---- block-aggregated exclusive scan -> start; also dis = rsqrt(deg) ----
__global__ void scan_kernel(const int* __restrict__ deg,
                            int* __restrict__ start,
                            float* __restrict__ dis, int* __restrict__ counter, int n) {
    __shared__ int waveSum[4];
    __shared__ int waveOff[4];
    __shared__ int blockBase;
    int i = blockIdx.x * 256 + threadIdx.x;
    int lane = threadIdx.x & 63;
    int w = threadIdx.x >> 6;
    int d = (i < n) ? deg[i] : 0;
    int incl = d;
    #pragma unroll
    for (int o = 1; o < 64; o <<= 1) {
        int v = __shfl_up(incl, o, 64);
        if (lane >= o) incl += v;
    }
    if (lane == 63) waveSum[w] = incl;
    __syncthreads();
    if (threadIdx.x == 0) {
        int t = 0;
        for (int k = 0; k < 4; k++) { waveOff[k] = t; t += waveSum[k]; }
        blockBase = atomicAdd(counter, t);
    }
    __syncthreads();
    if (i < n) {
        start[i] = blockBase + waveOff[w] + incl - d;
        dis[i] = (d > 0) ? rsqrtf((float)d) : 0.0f;
    }
}

// ---- atomic-free CSR scatter: slot = start[col[e]] + rank[e] ----
__global__ void scatter_kernel(const int* __restrict__ row, const int* __restrict__ col,
                               const int* __restrict__ start, const int* __restrict__ rank,
                               int* __restrict__ edge_src, int n_edges) {
    int e = blockIdx.x * blockDim.x + threadIdx.x;
    if (e < n_edges) {
        edge_src[start[col[e]] + rank[e]] = row[e];
    }
}

// ---- xs[node] = x[node] * dis[node], packed fp16 (24 half2 per node) ----
__global__ void prescale_kernel(const float* __restrict__ x, const float* __restrict__ dis,
                                __half2* __restrict__ xs, int n2) {
    int i = blockIdx.x * 256 + threadIdx.x;   // over N_NODES*24 half2 slots
    if (i < n2) {
        int node = i / 24;
        float2 v = ((const float2*)x)[i];     // pair i covers x[2i], x[2i+1]
        float d = dis[node];
        xs[i] = __floats2half2_rn(v.x * d, v.y * d);
    }
}

// ---- gather round 1: 8 lanes/node, 3x half2 per lane, fp32 accum ----
// h1[i] = (sum_src xs[src]) * dis[i]^2   (folds round-2 source scaling)
__global__ void gather1_kernel(const __half2* __restrict__ xs,
                               const int* __restrict__ start,
                               const int* __restrict__ deg,
                               const int* __restrict__ edge_src,
                               const float* __restrict__ dis,
                               __half2* __restrict__ h1) {
    int g = blockIdx.x * 32 + (threadIdx.x >> 3);
    int lane = threadIdx.x & 7;
    float a0 = 0, a1 = 0, a2 = 0, a3 = 0, a4 = 0, a5 = 0;
    int s = start[g], e = s + deg[g];
    for (int j = s; j < e; ++j) {
        int src = edge_src[j];
        const __half2* p = xs + src * 24 + lane;
        float2 v0 = __half22float2(p[0]);
        float2 v1 = __half22float2(p[8]);
        float2 v2 = __half22float2(p[16]);
        a0 += v0.x; a1 += v0.y; a2 += v1.x; a3 += v1.y; a4 += v2.x; a5 += v2.y;
    }
    float d = dis[g];
    float sc = d * d;
    __half2* q = h1 + g * 24 + lane;
    q[0]  = __floats2half2_rn(a0 * sc, a1 * sc);
    q[8]  = __floats2half2_rn(a2 * sc, a3 * sc);
    q[16] = __floats2half2_rn(a4 * sc, a5 * sc);
}

// ---- gather round 2 fused with GEMM ----
// Phase A: gather h2[i] = (sum h1[src]) * dis[i] into LDS (32 nodes/block).
// Phase B: out[i,:] = h2[i,:] @ W + b, 8 outputs per thread.
__global__ void gather2_gemm_kernel(const __half2* __restrict__ h1,
                                    const int* __restrict__ start,
                                    const int* __restrict__ deg,
                                    const int* __restrict__ edge_src,
                                    const float* __restrict__ dis,
                                    const float* __restrict__ W,
                                    const float* __restrict__ b,
                                    float* __restrict__ out) {
    __shared__ float sW[IN_CH * OUT_CH];
    __shared__ float sb[OUT_CH];
    __shared__ float sh[32][IN_CH + 1];

    for (int i = threadIdx.x; i < IN_CH * OUT_CH; i += 256) sW[i] = W[i];
    if (threadIdx.x < OUT_CH) sb[threadIdx.x] = b[threadIdx.x];

    int nl = threadIdx.x >> 3;       // 0..31 local node
    int lane = threadIdx.x & 7;      // 0..7
    int g = blockIdx.x * 32 + nl;

    float a0 = 0, a1 = 0, a2 = 0, a3 = 0, a4 = 0, a5 = 0;
    int s = start[g], e = s + deg[g];
    for (int j = s; j < e; ++j) {
        int src = edge_src[j];
        const __half2* p = h1 + src * 24 + lane;
        float2 v0 = __half22float2(p[0]);
        float2 v1 = __half22float2(p[8]);
        float2 v2 = __half22float2(p[16]);
        a0 += v0.x; a1 += v0.y; a2 += v1.x; a3 += v1.y; a4 += v2.x; a5 += v2.y;
    }
    float sc = dis[g];
    sh[nl][2 * lane]      = a0 * sc;
    sh[nl][2 * lane + 1]  = a1 * sc;
    sh[nl][2 * lane + 16] = a2 * sc;
    sh[nl][2 * lane + 17] = a3 * sc;
    sh[nl][2 * lane + 32] = a4 * sc;
    sh[nl][2 * lane + 33] = a5 * sc;
    __syncthreads();

    int j0 = lane * 8;
    float acc[8];
    #pragma unroll
    for (int i = 0; i < 8; i++) acc[i] = sb[j0 + i];
    for (int k = 0; k < IN_CH; k++) {
        float s0 = sh[nl][k];
        #pragma unroll
        for (int i = 0; i < 8; i++) acc[i] += s0 * sW[k * OUT_CH + j0 + i];
    }
    float4* o = (float4*)(out + (size_t)g * OUT_CH + j0);
    o[0] = make_float4(acc[0], acc[1], acc[2], acc[3]);
    o[1] = make_float4(acc[4], acc[5], acc[6], acc[7]);
}

extern "C" void kernel_launch(void* const* d_in, const int* in_sizes, int n_in,
                              void* d_out, int out_size, void* d_ws, size_t ws_size,
                              hipStream_t stream) {
    const float* x   = (const float*)d_in[0];
    const int*   ei  = (const int*)d_in[1];
    const float* W   = (const float*)d_in[2];
    const float* b   = (const float*)d_in[3];
    float* out = (float*)d_out;

    const int* row = ei;             // edge_index[0] (sources)
    const int* col = ei + N_EDGES;   // edge_index[1] (destinations)

    // ws layout (~33.2 MB, same footprint as R2):
    int* ws_i = (int*)d_ws;
    int* deg      = ws_i;                        // [100000], counter at +100000, pad 100352
    int* counter  = ws_i + 100000;
    int* start    = ws_i + 100352;               // [100000] pad 100352
    float* dis    = (float*)(start + 100352);    // [100000] pad 100352
    int* rank     = (int*)(dis + 100352);        // [1600000]
    int* edge_src = rank + N_EDGES;              // [1600000]
    __half2* xs   = (__half2*)(edge_src + N_EDGES);   // [2400000] half2 = 9.6 MB
    __half2* h1   = xs + (size_t)N_NODES * 24;        // [2400000] half2 = 9.6 MB

    hipMemsetAsync(deg, 0, 100352 * sizeof(int), stream);  // deg + counter

    degree_rank_kernel<<<(N_EDGES + 255) / 256, 256, 0, stream>>>(col, deg, rank, N_EDGES);
    scan_kernel<<<(N_NODES + 255) / 256, 256, 0, stream>>>(deg, start, dis, counter, N_NODES);
    prescale_kernel<<<(N_NODES * 24 + 255) / 256, 256, 0, stream>>>(x, dis, xs, N_NODES * 24);
    scatter_kernel<<<(N_EDGES + 255) / 256, 256, 0, stream>>>(row, col, start, rank, edge_src, N_EDGES);

    // 32 nodes per 256-thread block; 100000/32 = 3125 exactly
    gather1_kernel<<<N_NODES / 32, 256, 0, stream>>>(xs, start, deg, edge_src, dis, h1);
    gather2_gemm_kernel<<<N_NODES / 32, 256, 0, stream>>>(h1, start, deg, edge_src, dis, W, b, out);
}

// Round 5
// 288.491 us; speedup vs baseline: 7.5306x; 1.0180x over previous
//
#include <hip/hip_runtime.h>
#include <hip/hip_bf16.h>
#include <hip/hip_fp16.h>

// SGC: out = (D^-1/2 A D^-1/2)^2 x W + b.
// R4: degree-bucketed node ordering (equal-degree nodes grouped -> no
// intra-wave trip-count divergence in gathers) + gather loops unrolled x2
// (two independent miss chains). fp16 staging + fused gather2+GEMM from R3.

#define N_NODES 100000
#define N_EDGES 1600000
#define IN_CH 48
#define OUT_CH 64
#define NBINS 64

// ---- degree histogram over col; side-output: per-edge rank within node ----
__global__ void degree_rank_kernel(const int* __restrict__ col, int* __restrict__ deg,
                                   int* __restrict__ rank, int n_edges) {
    int e = blockIdx.x * blockDim.x + threadIdx.x;
    if (e < n_edges) {
        rank[e] = atomicAdd(&deg[col[e]], 1);
    }
}

// ---- block-aggregated exclusive scan -> start; dis = rsqrt(deg);
//      also degree-bin histogram (LDS + 64 global atomics per block) ----
__global__ void scan_kernel(const int* __restrict__ deg,
                            int* __restrict__ start,
                            float* __restrict__ dis, int* __restrict__ counter,
                            int* __restrict__ binTotal, int n) {
    __shared__ int waveSum[4];
    __shared__ int waveOff[4];
    __shared__ int blockBase;
    __shared__ int lhist[NBINS];
    int i = blockIdx.x * 256 + threadIdx.x;
    int lane = threadIdx.x & 63;
    int w = threadIdx.x >> 6;
    if (threadIdx.x < NBINS) lhist[threadIdx.x] = 0;
    __syncthreads();
    int d = (i < n) ? deg[i] : 0;
    if (i < n) atomicAdd(&lhist[min(d, NBINS - 1)], 1);
    int incl = d;
    #pragma unroll
    for (int o = 1; o < 64; o <<= 1) {
        int v = __shfl_up(incl, o, 64);
        if (lane >= o) incl += v;
    }
    if (lane == 63) waveSum[w] = incl;
    __syncthreads();
    if (threadIdx.x == 0) {
        int t = 0;
        for (int k = 0; k < 4; k++) { waveOff[k] = t; t += waveSum[k]; }
        blockBase = atomicAdd(counter, t);
    }
    __syncthreads();
    if (threadIdx.x < NBINS && lhist[threadIdx.x] > 0)
        atomicAdd(&binTotal[threadIdx.x], lhist[threadIdx.x]);
    if (i < n) {
        start[i] = blockBase + waveOff[w] + incl - d;
        dis[i] = (d > 0) ? rsqrtf((float)d) : 0.0f;
    }
}

// ---- tiny exclusive scan of 64 bin totals -> binCursor ----
__global__ void binscan_kernel(const int* __restrict__ binTotal, int* __restrict__ binCursor) {
    if (threadIdx.x == 0) {
        int t = 0;
        for (int k = 0; k < NBINS; k++) { binCursor[k] = t; t += binTotal[k]; }
    }
}

// ---- build degree-sorted order: equal-degree nodes contiguous ----
__global__ void order_kernel(const int* __restrict__ deg, int* __restrict__ binCursor,
                             int* __restrict__ order, int n) {
    __shared__ int lhist[NBINS];
    __shared__ int lbase[NBINS];
    int i = blockIdx.x * 256 + threadIdx.x;
    if (threadIdx.x < NBINS) lhist[threadIdx.x] = 0;
    __syncthreads();
    int bin = 0, myrank = 0;
    if (i < n) {
        bin = min(deg[i], NBINS - 1);
        myrank = atomicAdd(&lhist[bin], 1);
    }
    __syncthreads();
    if (threadIdx.x < NBINS && lhist[threadIdx.x] > 0)
        lbase[threadIdx.x] = atomicAdd(&binCursor[threadIdx.x], lhist[threadIdx.x]);
    __syncthreads();
    if (i < n) order[lbase[bin] + myrank] = i;
}

// ---- atomic-free CSR scatter: slot = start[col[e]] + rank[e] ----
__global__ void scatter_kernel(const int* __restrict__ row, const int* __restrict__ col,
                               const int* __restrict__ start, const int* __restrict__ rank,
                               int* __restrict__ edge_src, int n_edges) {
    int e = blockIdx.x * blockDim.x + threadIdx.x;
    if (e < n_edges) {
        edge_src[start[col[e]] + rank[e]] = row[e];
    }
}

// ---- xs[node] = x[node] * dis[node], packed fp16 (24 half2 per node) ----
__global__ void prescale_kernel(const float* __restrict__ x, const float* __restrict__ dis,
                                __half2* __restrict__ xs, int n2) {
    int i = blockIdx.x * 256 + threadIdx.x;
    if (i < n2) {
        int node = i / 24;
        float2 v = ((const float2*)x)[i];
        float d = dis[node];
        xs[i] = __floats2half2_rn(v.x * d, v.y * d);
    }
}

// ---- gather round 1: 8 lanes/node (via order), unrolled x2, fp32 accum ----
// h1[i] = (sum_src xs[src]) * dis[i]^2
__global__ void gather1_kernel(const __half2* __restrict__ xs,
                               const int* __restrict__ start,
                               const int* __restrict__ deg,
                               const int* __restrict__ edge_src,
                               const float* __restrict__ dis,
                               const int* __restrict__ order,
                               __half2* __restrict__ h1) {
    int g = blockIdx.x * 32 + (threadIdx.x >> 3);
    int lane = threadIdx.x & 7;
    int node = order[g];
    float a0 = 0, a1 = 0, a2 = 0, a3 = 0, a4 = 0, a5 = 0;
    float b0 = 0, b1 = 0, b2 = 0, b3 = 0, b4 = 0, b5 = 0;
    int s = start[node], e = s + deg[node];
    int j = s;
    for (; j + 1 < e; j += 2) {
        int s0 = edge_src[j];
        int s1 = edge_src[j + 1];
        const __half2* p0 = xs + s0 * 24 + lane;
        const __half2* p1 = xs + s1 * 24 + lane;
        float2 u0 = __half22float2(p0[0]);
        float2 u1 = __half22float2(p0[8]);
        float2 u2 = __half22float2(p0[16]);
        float2 w0 = __half22float2(p1[0]);
        float2 w1 = __half22float2(p1[8]);
        float2 w2 = __half22float2(p1[16]);
        a0 += u0.x; a1 += u0.y; a2 += u1.x; a3 += u1.y; a4 += u2.x; a5 += u2.y;
        b0 += w0.x; b1 += w0.y; b2 += w1.x; b3 += w1.y; b4 += w2.x; b5 += w2.y;
    }
    if (j < e) {
        int s0 = edge_src[j];
        const __half2* p0 = xs + s0 * 24 + lane;
        float2 u0 = __half22float2(p0[0]);
        float2 u1 = __half22float2(p0[8]);
        float2 u2 = __half22float2(p0[16]);
        a0 += u0.x; a1 += u0.y; a2 += u1.x; a3 += u1.y; a4 += u2.x; a5 += u2.y;
    }
    a0 += b0; a1 += b1; a2 += b2; a3 += b3; a4 += b4; a5 += b5;
    float d = dis[node];
    float sc = d * d;
    __half2* q = h1 + node * 24 + lane;
    q[0]  = __floats2half2_rn(a0 * sc, a1 * sc);
    q[8]  = __floats2half2_rn(a2 * sc, a3 * sc);
    q[16] = __floats2half2_rn(a4 * sc, a5 * sc);
}

// ---- gather round 2 fused with GEMM (nodes via order) ----
__global__ void gather2_gemm_kernel(const __half2* __restrict__ h1,
                                    const int* __restrict__ start,
                                    const int* __restrict__ deg,
                                    const int* __restrict__ edge_src,
                                    const float* __restrict__ dis,
                                    const int* __restrict__ order,
                                    const float* __restrict__ W,
                                    const float* __restrict__ b,
                                    float* __restrict__ out) {
    __shared__ float sW[IN_CH * OUT_CH];
    __shared__ float sb[OUT_CH];
    __shared__ float sh[32][IN_CH + 1];

    for (int i = threadIdx.x; i < IN_CH * OUT_CH; i += 256) sW[i] = W[i];
    if (threadIdx.x < OUT_CH) sb[threadIdx.x] = b[threadIdx.x];

    int nl = threadIdx.x >> 3;
    int lane = threadIdx.x & 7;
    int g = blockIdx.x * 32 + nl;
    int node = order[g];

    float a0 = 0, a1 = 0, a2 = 0, a3 = 0, a4 = 0, a5 = 0;
    float c0 = 0, c1 = 0, c2 = 0, c3 = 0, c4 = 0, c5 = 0;
    int s = start[node], e = s + deg[node];
    int j = s;
    for (; j + 1 < e; j += 2) {
        int s0 = edge_src[j];
        int s1 = edge_src[j + 1];
        const __half2* p0 = h1 + s0 * 24 + lane;
        const __half2* p1 = h1 + s1 * 24 + lane;
        float2 u0 = __half22float2(p0[0]);
        float2 u1 = __half22float2(p0[8]);
        float2 u2 = __half22float2(p0[16]);
        float2 w0 = __half22float2(p1[0]);
        float2 w1 = __half22float2(p1[8]);
        float2 w2 = __half22float2(p1[16]);
        a0 += u0.x; a1 += u0.y; a2 += u1.x; a3 += u1.y; a4 += u2.x; a5 += u2.y;
        c0 += w0.x; c1 += w0.y; c2 += w1.x; c3 += w1.y; c4 += w2.x; c5 += w2.y;
    }
    if (j < e) {
        int s0 = edge_src[j];
        const __half2* p0 = h1 + s0 * 24 + lane;
        float2 u0 = __half22float2(p0[0]);
        float2 u1 = __half22float2(p0[8]);
        float2 u2 = __half22float2(p0[16]);
        a0 += u0.x; a1 += u0.y; a2 += u1.x; a3 += u1.y; a4 += u2.x; a5 += u2.y;
    }
    a0 += c0; a1 += c1; a2 += c2; a3 += c3; a4 += c4; a5 += c5;
    float sc = dis[node];
    sh[nl][2 * lane]      = a0 * sc;
    sh[nl][2 * lane + 1]  = a1 * sc;
    sh[nl][2 * lane + 16] = a2 * sc;
    sh[nl][2 * lane + 17] = a3 * sc;
    sh[nl][2 * lane + 32] = a4 * sc;
    sh[nl][2 * lane + 33] = a5 * sc;
    __syncthreads();

    int j0 = lane * 8;
    float acc[8];
    #pragma unroll
    for (int i = 0; i < 8; i++) acc[i] = sb[j0 + i];
    for (int k = 0; k < IN_CH; k++) {
        float s0 = sh[nl][k];
        #pragma unroll
        for (int i = 0; i < 8; i++) acc[i] += s0 * sW[k * OUT_CH + j0 + i];
    }
    float4* o = (float4*)(out + (size_t)node * OUT_CH + j0);
    o[0] = make_float4(acc[0], acc[1], acc[2], acc[3]);
    o[1] = make_float4(acc[4], acc[5], acc[6], acc[7]);
}

extern "C" void kernel_launch(void* const* d_in, const int* in_sizes, int n_in,
                              void* d_out, int out_size, void* d_ws, size_t ws_size,
                              hipStream_t stream) {
    const float* x   = (const float*)d_in[0];
    const int*   ei  = (const int*)d_in[1];
    const float* W   = (const float*)d_in[2];
    const float* b   = (const float*)d_in[3];
    float* out = (float*)d_out;

    const int* row = ei;             // edge_index[0] (sources)
    const int* col = ei + N_EDGES;   // edge_index[1] (destinations)

    // ws layout (4-byte elems), ~34.0 MB:
    int* ws_i = (int*)d_ws;
    int* deg       = ws_i;                        // [100000]
    int* counter   = ws_i + 100000;               // [1]
    int* binTotal  = ws_i + 100004;               // [64]
    int* binCursor = ws_i + 100068;               // [64] (written by binscan)
    int* start     = ws_i + 100352;               // [100000] pad 100352
    float* dis     = (float*)(start + 100352);    // [100000] pad 100352
    int* order     = (int*)(dis + 100352);        // [100000] pad 100352
    int* rank      = order + 100352;              // [1600000]
    int* edge_src  = rank + N_EDGES;              // [1600000]
    __half2* xs    = (__half2*)(edge_src + N_EDGES);  // [2400000] = 9.6 MB
    __half2* h1    = xs + (size_t)N_NODES * 24;       // [2400000] = 9.6 MB

    // zeroes deg, counter, binTotal (binCursor overwritten by binscan)
    hipMemsetAsync(deg, 0, 100352 * sizeof(int), stream);

    degree_rank_kernel<<<(N_EDGES + 255) / 256, 256, 0, stream>>>(col, deg, rank, N_EDGES);
    scan_kernel<<<(N_NODES + 255) / 256, 256, 0, stream>>>(deg, start, dis, counter, binTotal, N_NODES);
    binscan_kernel<<<1, 64, 0, stream>>>(binTotal, binCursor);
    order_kernel<<<(N_NODES + 255) / 256, 256, 0, stream>>>(deg, binCursor, order, N_NODES);
    prescale_kernel<<<(N_NODES * 24 + 255) / 256, 256, 0, stream>>>(x, dis, xs, N_NODES * 24);
    scatter_kernel<<<(N_EDGES + 255) / 256, 256, 0, stream>>>(row, col, start, rank, edge_src, N_EDGES);

    // 32 nodes per 256-thread block; 100000/32 = 3125 exactly
    gather1_kernel<<<N_NODES / 32, 256, 0, stream>>>(xs, start, deg, edge_src, dis, order, h1);
    gather2_gemm_kernel<<<N_NODES / 32, 256, 0, stream>>>(h1, start, deg, edge_src, dis, order, W, b, out);
}

// Round 6
// 262.004 us; speedup vs baseline: 8.2919x; 1.1011x over previous
//
#include <hip/hip_runtime.h>
#include <hip/hip_bf16.h>
#include <hip/hip_fp16.h>

// SGC: out = (D^-1/2 A D^-1/2)^2 x W + b.
// R5: sort-based CSR build (two-level counting sort: 1024 coarse buckets of
// 128 nodes, then per-bucket fine sort). Cuts device-scope atomics from 1.6M+
// to ~360K aggregated ones; everything else is LDS atomics + pure stores.
// fp16 staging, degree-bucketed gather order, fused gather2+GEMM from R3/R4.

#define N_NODES 100000
#define N_EDGES 1600000
#define IN_CH 48
#define OUT_CH 64
#define NBINS 64
#define NBUCKETS 1024            // bucket = col >> 7 (128 nodes each)
#define EDGES_PER_BLOCK 8192     // 256 threads x 32
#define NBLK_EDGE 196            // ceil(1.6M / 8192)

// ---- Pass A1: coarse bucket histogram (LDS-privatized) ----
__global__ void bucket_hist_kernel(const int* __restrict__ col, int* __restrict__ bucketCount) {
    __shared__ int lh[NBUCKETS];
    for (int i = threadIdx.x; i < NBUCKETS; i += 256) lh[i] = 0;
    __syncthreads();
    int base = blockIdx.x * EDGES_PER_BLOCK;
    #pragma unroll 4
    for (int k = 0; k < 32; k++) {
        int e = base + k * 256 + threadIdx.x;
        if (e < N_EDGES) atomicAdd(&lh[col[e] >> 7], 1);
    }
    __syncthreads();
    for (int i = threadIdx.x; i < NBUCKETS; i += 256)
        if (lh[i]) atomicAdd(&bucketCount[i], lh[i]);
}

// ---- Pass A2: exclusive scan of bucket counts ----
__global__ void bucket_scan_kernel(const int* __restrict__ bucketCount,
                                   int* __restrict__ bucketStart,
                                   int* __restrict__ bucketCursor) {
    __shared__ int l[NBUCKETS + 1];
    for (int i = threadIdx.x; i < NBUCKETS; i += 256) l[i] = bucketCount[i];
    __syncthreads();
    if (threadIdx.x == 0) {
        int t = 0;
        for (int k = 0; k < NBUCKETS; k++) { int c = l[k]; l[k] = t; t += c; }
        l[NBUCKETS] = t;
    }
    __syncthreads();
    for (int i = threadIdx.x; i <= NBUCKETS; i += 256) {
        bucketStart[i] = l[i];
        if (i < NBUCKETS) bucketCursor[i] = l[i];
    }
}

// ---- Pass A3: scatter (row,col) pairs into bucket-contiguous regions ----
// One reservation atomic per (block,bucket); per-edge ranks via LDS atomics.
__global__ void bucket_scatter_kernel(const int* __restrict__ row, const int* __restrict__ col,
                                      int* __restrict__ bucketCursor, int2* __restrict__ bucketed) {
    __shared__ int lh[NBUCKETS];
    __shared__ int lbase[NBUCKETS];
    for (int i = threadIdx.x; i < NBUCKETS; i += 256) lh[i] = 0;
    __syncthreads();
    int base = blockIdx.x * EDGES_PER_BLOCK;
    #pragma unroll 4
    for (int k = 0; k < 32; k++) {
        int e = base + k * 256 + threadIdx.x;
        if (e < N_EDGES) atomicAdd(&lh[col[e] >> 7], 1);
    }
    __syncthreads();
    for (int i = threadIdx.x; i < NBUCKETS; i += 256)
        if (lh[i]) lbase[i] = atomicAdd(&bucketCursor[i], lh[i]);
    __syncthreads();
    for (int i = threadIdx.x; i < NBUCKETS; i += 256) lh[i] = 0;
    __syncthreads();
    #pragma unroll 4
    for (int k = 0; k < 32; k++) {
        int e = base + k * 256 + threadIdx.x;
        if (e < N_EDGES) {
            int c = col[e];
            int bkt = c >> 7;
            int r = atomicAdd(&lh[bkt], 1);
            bucketed[lbase[bkt] + r] = make_int2(row[e], c);
        }
    }
}

// ---- Pass B: per-bucket fine counting sort -> edge_src, deg, start, dis ----
// One block per bucket (128 nodes). Two passes over the bucket's edges
// (second read is L2/L3-warm). Zero global atomics except bin histogram.
__global__ void fine_sort_kernel(const int2* __restrict__ bucketed,
                                 const int* __restrict__ bucketStart,
                                 int* __restrict__ edge_src,
                                 int* __restrict__ deg, int* __restrict__ start,
                                 float* __restrict__ dis, int* __restrict__ binTotal) {
    __shared__ int fh[128];
    __shared__ int sfh[129];
    __shared__ int cur[128];
    __shared__ int bh[NBINS];
    int b = blockIdx.x;
    int s0 = bucketStart[b], s1 = bucketStart[b + 1];
    if (threadIdx.x < 128) fh[threadIdx.x] = 0;
    if (threadIdx.x < NBINS) bh[threadIdx.x] = 0;
    __syncthreads();
    for (int j = s0 + threadIdx.x; j < s1; j += 256)
        atomicAdd(&fh[bucketed[j].y & 127], 1);
    __syncthreads();
    if (threadIdx.x == 0) {
        int t = 0;
        for (int k = 0; k < 128; k++) { sfh[k] = t; t += fh[k]; }
        sfh[128] = t;
    }
    __syncthreads();
    if (threadIdx.x < 128) {
        cur[threadIdx.x] = sfh[threadIdx.x];
        int node = b * 128 + threadIdx.x;
        if (node < N_NODES) {
            int d = fh[threadIdx.x];
            deg[node] = d;
            start[node] = s0 + sfh[threadIdx.x];
            dis[node] = (d > 0) ? rsqrtf((float)d) : 0.0f;
            atomicAdd(&bh[min(d, NBINS - 1)], 1);
        }
    }
    __syncthreads();
    for (int j = s0 + threadIdx.x; j < s1; j += 256) {
        int2 rc = bucketed[j];
        int p = atomicAdd(&cur[rc.y & 127], 1);
        edge_src[s0 + p] = rc.x;
    }
    __syncthreads();
    if (threadIdx.x < NBINS && bh[threadIdx.x])
        atomicAdd(&binTotal[threadIdx.x], bh[threadIdx.x]);
}

// ---- tiny exclusive scan of 64 degree-bin totals ----
__global__ void binscan_kernel(const int* __restrict__ binTotal, int* __restrict__ binCursor) {
    if (threadIdx.x == 0) {
        int t = 0;
        for (int k = 0; k < NBINS; k++) { binCursor[k] = t; t += binTotal[k]; }
    }
}

// ---- build degree-sorted order: equal-degree nodes contiguous ----
__global__ void order_kernel(const int* __restrict__ deg, int* __restrict__ binCursor,
                             int* __restrict__ order, int n) {
    __shared__ int lhist[NBINS];
    __shared__ int lbase[NBINS];
    int i = blockIdx.x * 256 + threadIdx.x;
    if (threadIdx.x < NBINS) lhist[threadIdx.x] = 0;
    __syncthreads();
    int bin = 0, myrank = 0;
    if (i < n) {
        bin = min(deg[i], NBINS - 1);
        myrank = atomicAdd(&lhist[bin], 1);
    }
    __syncthreads();
    if (threadIdx.x < NBINS && lhist[threadIdx.x] > 0)
        lbase[threadIdx.x] = atomicAdd(&binCursor[threadIdx.x], lhist[threadIdx.x]);
    __syncthreads();
    if (i < n) order[lbase[bin] + myrank] = i;
}

// ---- xs[node] = x[node] * dis[node], packed fp16 (24 half2 per node) ----
__global__ void prescale_kernel(const float* __restrict__ x, const float* __restrict__ dis,
                                __half2* __restrict__ xs, int n2) {
    int i = blockIdx.x * 256 + threadIdx.x;
    if (i < n2) {
        int node = i / 24;
        float2 v = ((const float2*)x)[i];
        float d = dis[node];
        xs[i] = __floats2half2_rn(v.x * d, v.y * d);
    }
}

// ---- gather round 1: 8 lanes/node (via order), unrolled x2, fp32 accum ----
__global__ void gather1_kernel(const __half2* __restrict__ xs,
                               const int* __restrict__ start,
                               const int* __restrict__ deg,
                               const int* __restrict__ edge_src,
                               const float* __restrict__ dis,
                               const int* __restrict__ order,
                               __half2* __restrict__ h1) {
    int g = blockIdx.x * 32 + (threadIdx.x >> 3);
    int lane = threadIdx.x & 7;
    int node = order[g];
    float a0 = 0, a1 = 0, a2 = 0, a3 = 0, a4 = 0, a5 = 0;
    float b0 = 0, b1 = 0, b2 = 0, b3 = 0, b4 = 0, b5 = 0;
    int s = start[node], e = s + deg[node];
    int j = s;
    for (; j + 1 < e; j += 2) {
        int s0 = edge_src[j];
        int s1 = edge_src[j + 1];
        const __half2* p0 = xs + s0 * 24 + lane;
        const __half2* p1 = xs + s1 * 24 + lane;
        float2 u0 = __half22float2(p0[0]);
        float2 u1 = __half22float2(p0[8]);
        float2 u2 = __half22float2(p0[16]);
        float2 w0 = __half22float2(p1[0]);
        float2 w1 = __half22float2(p1[8]);
        float2 w2 = __half22float2(p1[16]);
        a0 += u0.x; a1 += u0.y; a2 += u1.x; a3 += u1.y; a4 += u2.x; a5 += u2.y;
        b0 += w0.x; b1 += w0.y; b2 += w1.x; b3 += w1.y; b4 += w2.x; b5 += w2.y;
    }
    if (j < e) {
        int s0 = edge_src[j];
        const __half2* p0 = xs + s0 * 24 + lane;
        float2 u0 = __half22float2(p0[0]);
        float2 u1 = __half22float2(p0[8]);
        float2 u2 = __half22float2(p0[16]);
        a0 += u0.x; a1 += u0.y; a2 += u1.x; a3 += u1.y; a4 += u2.x; a5 += u2.y;
    }
    a0 += b0; a1 += b1; a2 += b2; a3 += b3; a4 += b4; a5 += b5;
    float d = dis[node];
    float sc = d * d;
    __half2* q = h1 + node * 24 + lane;
    q[0]  = __floats2half2_rn(a0 * sc, a1 * sc);
    q[8]  = __floats2half2_rn(a2 * sc, a3 * sc);
    q[16] = __floats2half2_rn(a4 * sc, a5 * sc);
}

// ---- gather round 2 fused with GEMM (nodes via order) ----
__global__ void gather2_gemm_kernel(const __half2* __restrict__ h1,
                                    const int* __restrict__ start,
                                    const int* __restrict__ deg,
                                    const int* __restrict__ edge_src,
                                    const float* __restrict__ dis,
                                    const int* __restrict__ order,
                                    const float* __restrict__ W,
                                    const float* __restrict__ b,
                                    float* __restrict__ out) {
    __shared__ float sW[IN_CH * OUT_CH];
    __shared__ float sb[OUT_CH];
    __shared__ float sh[32][IN_CH + 1];

    for (int i = threadIdx.x; i < IN_CH * OUT_CH; i += 256) sW[i] = W[i];
    if (threadIdx.x < OUT_CH) sb[threadIdx.x] = b[threadIdx.x];

    int nl = threadIdx.x >> 3;
    int lane = threadIdx.x & 7;
    int g = blockIdx.x * 32 + nl;
    int node = order[g];

    float a0 = 0, a1 = 0, a2 = 0, a3 = 0, a4 = 0, a5 = 0;
    float c0 = 0, c1 = 0, c2 = 0, c3 = 0, c4 = 0, c5 = 0;
    int s = start[node], e = s + deg[node];
    int j = s;
    for (; j + 1 < e; j += 2) {
        int s0 = edge_src[j];
        int s1 = edge_src[j + 1];
        const __half2* p0 = h1 + s0 * 24 + lane;
        const __half2* p1 = h1 + s1 * 24 + lane;
        float2 u0 = __half22float2(p0[0]);
        float2 u1 = __half22float2(p0[8]);
        float2 u2 = __half22float2(p0[16]);
        float2 w0 = __half22float2(p1[0]);
        float2 w1 = __half22float2(p1[8]);
        float2 w2 = __half22float2(p1[16]);
        a0 += u0.x; a1 += u0.y; a2 += u1.x; a3 += u1.y; a4 += u2.x; a5 += u2.y;
        c0 += w0.x; c1 += w0.y; c2 += w1.x; c3 += w1.y; c4 += w2.x; c5 += w2.y;
    }
    if (j < e) {
        int s0 = edge_src[j];
        const __half2* p0 = h1 + s0 * 24 + lane;
        float2 u0 = __half22float2(p0[0]);
        float2 u1 = __half22float2(p0[8]);
        float2 u2 = __half22float2(p0[16]);
        a0 += u0.x; a1 += u0.y; a2 += u1.x; a3 += u1.y; a4 += u2.x; a5 += u2.y;
    }
    a0 += c0; a1 += c1; a2 += c2; a3 += c3; a4 += c4; a5 += c5;
    float sc = dis[node];
    sh[nl][2 * lane]      = a0 * sc;
    sh[nl][2 * lane + 1]  = a1 * sc;
    sh[nl][2 * lane + 16] = a2 * sc;
    sh[nl][2 * lane + 17] = a3 * sc;
    sh[nl][2 * lane + 32] = a4 * sc;
    sh[nl][2 * lane + 33] = a5 * sc;
    __syncthreads();

    int j0 = lane * 8;
    float acc[8];
    #pragma unroll
    for (int i = 0; i < 8; i++) acc[i] = sb[j0 + i];
    for (int k = 0; k < IN_CH; k++) {
        float s0 = sh[nl][k];
        #pragma unroll
        for (int i = 0; i < 8; i++) acc[i] += s0 * sW[k * OUT_CH + j0 + i];
    }
    float4* o = (float4*)(out + (size_t)node * OUT_CH + j0);
    o[0] = make_float4(acc[0], acc[1], acc[2], acc[3]);
    o[1] = make_float4(acc[4], acc[5], acc[6], acc[7]);
}

extern "C" void kernel_launch(void* const* d_in, const int* in_sizes, int n_in,
                              void* d_out, int out_size, void* d_ws, size_t ws_size,
                              hipStream_t stream) {
    const float* x   = (const float*)d_in[0];
    const int*   ei  = (const int*)d_in[1];
    const float* W   = (const float*)d_in[2];
    const float* b   = (const float*)d_in[3];
    float* out = (float*)d_out;

    const int* row = ei;             // edge_index[0] (sources)
    const int* col = ei + N_EDGES;   // edge_index[1] (destinations)

    // ws layout (4-byte elems), ~30.4 MB total. bucketed (12.8 MB) is dead
    // after fine_sort; xs (9.6 MB) aliases it.
    int* ws_i = (int*)d_ws;
    int* bucketCount  = ws_i;                 // [1024]
    int* binTotal     = ws_i + 1024;          // [64]  (memset together with bucketCount)
    int* binCursor    = ws_i + 1088;          // [64]  (overwritten by binscan)
    int* bucketStart  = ws_i + 1152;          // [1025]
    int* bucketCursor = ws_i + 2208;          // [1024]
    int* deg          = ws_i + 3584;          // [100000] pad 100352
    int* start        = deg + 100352;         // [100000] pad 100352
    float* dis        = (float*)(start + 100352);  // [100000] pad 100352
    int* order        = (int*)(dis + 100352);      // [100000] pad 100352
    int* edge_src     = order + 100352;       // [1600000]
    int2* bucketed    = (int2*)(edge_src + N_EDGES);   // [1600000] int2 = 12.8 MB
    __half2* xs       = (__half2*)bucketed;            // aliases bucketed (9.6 MB)
    __half2* h1       = (__half2*)(edge_src + N_EDGES + 2 * N_EDGES);  // after bucketed, 9.6 MB

    hipMemsetAsync(bucketCount, 0, 1088 * sizeof(int), stream);  // bucketCount + binTotal

    bucket_hist_kernel<<<NBLK_EDGE, 256, 0, stream>>>(col, bucketCount);
    bucket_scan_kernel<<<1, 256, 0, stream>>>(bucketCount, bucketStart, bucketCursor);
    bucket_scatter_kernel<<<NBLK_EDGE, 256, 0, stream>>>(row, col, bucketCursor, bucketed);
    fine_sort_kernel<<<(N_NODES + 127) / 128, 256, 0, stream>>>(bucketed, bucketStart,
                                                                edge_src, deg, start, dis, binTotal);
    binscan_kernel<<<1, 64, 0, stream>>>(binTotal, binCursor);
    order_kernel<<<(N_NODES + 255) / 256, 256, 0, stream>>>(deg, binCursor, order, N_NODES);
    prescale_kernel<<<(N_NODES * 24 + 255) / 256, 256, 0, stream>>>(x, dis, xs, N_NODES * 24);

    // 32 nodes per 256-thread block; 100000/32 = 3125 exactly
    gather1_kernel<<<N_NODES / 32, 256, 0, stream>>>(xs, start, deg, edge_src, dis, order, h1);
    gather2_gemm_kernel<<<N_NODES / 32, 256, 0, stream>>>(h1, start, deg, edge_src, dis, order, W, b, out);
}

// Round 7
// 249.118 us; speedup vs baseline: 8.7208x; 1.0517x over previous
//
#include <hip/hip_runtime.h>
#include <hip/hip_bf16.h>
#include <hip/hip_fp16.h>

// SGC: out = (D^-1/2 A D^-1/2)^2 x W + b.
// R6: latency attack on gathers (x4 unroll, 12B/lane contiguous row chunks,
// descending-degree scheduling, packed int4 nodeinfo) + LDS-staged coalesced
// bucket scatter with packed (row<<7|col&127) edges.

#define N_NODES 100000
#define N_EDGES 1600000
#define IN_CH 48
#define OUT_CH 64
#define NBINS 64
#define NBUCKETS 1024            // bucket = col >> 7 (128 nodes each)
#define EPB 8192                 // edges per scatter block
#define NBLK_EDGE 196            // ceil(1.6M / 8192)

// ---- Pass A1: coarse bucket histogram (LDS-privatized) ----
__global__ void bucket_hist_kernel(const int* __restrict__ col, int* __restrict__ bucketCount) {
    __shared__ int lh[NBUCKETS];
    for (int i = threadIdx.x; i < NBUCKETS; i += 256) lh[i] = 0;
    __syncthreads();
    int base = blockIdx.x * EPB;
    #pragma unroll 4
    for (int k = 0; k < 32; k++) {
        int e = base + k * 256 + threadIdx.x;
        if (e < N_EDGES) atomicAdd(&lh[col[e] >> 7], 1);
    }
    __syncthreads();
    for (int i = threadIdx.x; i < NBUCKETS; i += 256)
        if (lh[i]) atomicAdd(&bucketCount[i], lh[i]);
}

// ---- Pass A2: exclusive scan of bucket counts ----
__global__ void bucket_scan_kernel(const int* __restrict__ bucketCount,
                                   int* __restrict__ bucketStart,
                                   int* __restrict__ bucketCursor) {
    __shared__ int l[NBUCKETS + 1];
    for (int i = threadIdx.x; i < NBUCKETS; i += 256) l[i] = bucketCount[i];
    __syncthreads();
    if (threadIdx.x == 0) {
        int t = 0;
        for (int k = 0; k < NBUCKETS; k++) { int c = l[k]; l[k] = t; t += c; }
        l[NBUCKETS] = t;
    }
    __syncthreads();
    for (int i = threadIdx.x; i <= NBUCKETS; i += 256) {
        bucketStart[i] = l[i];
        if (i < NBUCKETS) bucketCursor[i] = l[i];
    }
}

// ---- Pass A3: LDS-staged scatter of packed edges into bucket regions ----
// Stage all 8192 edges in LDS sorted by bucket, then copy out so consecutive
// threads write consecutive slots (coalesced bursts per bucket run).
__global__ void bucket_scatter_kernel(const int* __restrict__ row, const int* __restrict__ col,
                                      int* __restrict__ bucketCursor, int* __restrict__ bucketed) {
    __shared__ int lh[NBUCKETS];
    __shared__ int lofs[NBUCKETS];
    __shared__ int lbase[NBUCKETS];
    __shared__ int stage[EPB];
    __shared__ unsigned short sbkt[EPB];
    __shared__ int wsum[4];
    int tid = threadIdx.x;
    int base = blockIdx.x * EPB;
    for (int i = tid; i < NBUCKETS; i += 256) lh[i] = 0;
    __syncthreads();
    // count
    #pragma unroll 4
    for (int k = 0; k < 32; k++) {
        int e = base + k * 256 + tid;
        if (e < N_EDGES) atomicAdd(&lh[col[e] >> 7], 1);
    }
    __syncthreads();
    // parallel exclusive scan of 1024 counts (4 buckets per thread)
    int c0 = lh[4 * tid], c1 = lh[4 * tid + 1], c2 = lh[4 * tid + 2], c3 = lh[4 * tid + 3];
    {
        int s = c0 + c1 + c2 + c3;
        int incl = s;
        int lane = tid & 63, w = tid >> 6;
        #pragma unroll
        for (int o = 1; o < 64; o <<= 1) {
            int v = __shfl_up(incl, o, 64);
            if (lane >= o) incl += v;
        }
        if (lane == 63) wsum[w] = incl;
        __syncthreads();
        int wbase = 0;
        for (int k = 0; k < w; k++) wbase += wsum[k];
        int ex = wbase + incl - s;
        lofs[4 * tid]     = ex;
        lofs[4 * tid + 1] = ex + c0;
        lofs[4 * tid + 2] = ex + c0 + c1;
        lofs[4 * tid + 3] = ex + c0 + c1 + c2;
    }
    __syncthreads();
    // global reservation (one atomic per non-empty bucket) + reset counters
    for (int i = tid; i < NBUCKETS; i += 256) {
        int c = lh[i];
        if (c > 0) lbase[i] = atomicAdd(&bucketCursor[i], c);
        lh[i] = 0;
    }
    __syncthreads();
    // stage edges (packed: row<<7 | col&127), record bucket per slot
    #pragma unroll 4
    for (int k = 0; k < 32; k++) {
        int e = base + k * 256 + tid;
        if (e < N_EDGES) {
            int c = col[e];
            int bkt = c >> 7;
            int r = atomicAdd(&lh[bkt], 1);
            int slot = lofs[bkt] + r;
            stage[slot] = (row[e] << 7) | (c & 127);
            sbkt[slot] = (unsigned short)bkt;
        }
    }
    __syncthreads();
    // coalesced copy-out
    int total = (base + EPB <= N_EDGES) ? EPB : (N_EDGES - base);
    for (int i = tid; i < total; i += 256) {
        int bkt = sbkt[i];
        bucketed[lbase[bkt] + (i - lofs[bkt])] = stage[i];
    }
}

// ---- Pass B: per-bucket fine counting sort -> edge_src, deg, start, dis ----
__global__ void fine_sort_kernel(const int* __restrict__ bucketed,
                                 const int* __restrict__ bucketStart,
                                 int* __restrict__ edge_src,
                                 int* __restrict__ deg, int* __restrict__ start,
                                 float* __restrict__ dis, int* __restrict__ binTotal) {
    __shared__ int fh[128];
    __shared__ int sfh[129];
    __shared__ int cur[128];
    __shared__ int bh[NBINS];
    int b = blockIdx.x;
    int s0 = bucketStart[b], s1 = bucketStart[b + 1];
    if (threadIdx.x < 128) fh[threadIdx.x] = 0;
    if (threadIdx.x < NBINS) bh[threadIdx.x] = 0;
    __syncthreads();
    for (int j = s0 + threadIdx.x; j < s1; j += 256)
        atomicAdd(&fh[bucketed[j] & 127], 1);
    __syncthreads();
    if (threadIdx.x == 0) {
        int t = 0;
        for (int k = 0; k < 128; k++) { sfh[k] = t; t += fh[k]; }
        sfh[128] = t;
    }
    __syncthreads();
    if (threadIdx.x < 128) {
        cur[threadIdx.x] = sfh[threadIdx.x];
        int node = b * 128 + threadIdx.x;
        if (node < N_NODES) {
            int d = fh[threadIdx.x];
            deg[node] = d;
            start[node] = s0 + sfh[threadIdx.x];
            dis[node] = (d > 0) ? rsqrtf((float)d) : 0.0f;
            atomicAdd(&bh[min(d, NBINS - 1)], 1);
        }
    }
    __syncthreads();
    for (int j = s0 + threadIdx.x; j < s1; j += 256) {
        int rc = bucketed[j];
        int p = atomicAdd(&cur[rc & 127], 1);
        edge_src[s0 + p] = rc >> 7;
    }
    __syncthreads();
    if (threadIdx.x < NBINS && bh[threadIdx.x])
        atomicAdd(&binTotal[threadIdx.x], bh[threadIdx.x]);
}

// ---- exclusive scan of degree bins, DESCENDING (heavy nodes first) ----
__global__ void binscan_kernel(const int* __restrict__ binTotal, int* __restrict__ binCursor) {
    if (threadIdx.x == 0) {
        int t = 0;
        for (int k = NBINS - 1; k >= 0; k--) { binCursor[k] = t; t += binTotal[k]; }
    }
}

// ---- build degree-sorted nodeinfo: {node, start, deg, dis} packed int4 ----
__global__ void order_kernel(const int* __restrict__ deg, const int* __restrict__ start,
                             const float* __restrict__ dis, int* __restrict__ binCursor,
                             int4* __restrict__ nodeinfo, int n) {
    __shared__ int lhist[NBINS];
    __shared__ int lbase[NBINS];
    int i = blockIdx.x * 256 + threadIdx.x;
    if (threadIdx.x < NBINS) lhist[threadIdx.x] = 0;
    __syncthreads();
    int bin = 0, myrank = 0;
    if (i < n) {
        bin = min(deg[i], NBINS - 1);
        myrank = atomicAdd(&lhist[bin], 1);
    }
    __syncthreads();
    if (threadIdx.x < NBINS && lhist[threadIdx.x] > 0)
        lbase[threadIdx.x] = atomicAdd(&binCursor[threadIdx.x], lhist[threadIdx.x]);
    __syncthreads();
    if (i < n) {
        int pos = lbase[bin] + myrank;
        nodeinfo[pos] = make_int4(i, start[i], deg[i], __float_as_int(dis[i]));
    }
}

// ---- xs[node] = x[node] * dis[node], packed fp16 (24 half2 per node) ----
__global__ void prescale_kernel(const float* __restrict__ x, const float* __restrict__ dis,
                                __half2* __restrict__ xs, int n2) {
    int i = blockIdx.x * 256 + threadIdx.x;
    if (i < n2) {
        int node = i / 24;
        float2 v = ((const float2*)x)[i];
        float d = dis[node];
        xs[i] = __floats2half2_rn(v.x * d, v.y * d);
    }
}

// Per-lane row chunk: 3 consecutive half2 at row*24 + lane*3 (12 B contiguous).
#define LOAD3(p, v0, v1, v2) { v0 = (p)[0]; v1 = (p)[1]; v2 = (p)[2]; }
#define ACC6(v0, v1, v2) { \
    float2 u0 = __half22float2(v0), u1 = __half22float2(v1), u2 = __half22float2(v2); \
    a0 += u0.x; a1 += u0.y; a2 += u1.x; a3 += u1.y; a4 += u2.x; a5 += u2.y; }

// ---- gather round 1: 8 lanes/node, x4 unroll, fp32 accum ----
// h1[i] = (sum_src xs[src]) * dis[i]^2   (folds round-2 source scaling)
__global__ void gather1_kernel(const __half2* __restrict__ xs,
                               const int* __restrict__ edge_src,
                               const int4* __restrict__ nodeinfo,
                               __half2* __restrict__ h1) {
    int g = blockIdx.x * 32 + (threadIdx.x >> 3);
    int lane = threadIdx.x & 7;
    int4 ni = nodeinfo[g];
    int node = ni.x, s = ni.y, e = ni.y + ni.z;
    float dv = __int_as_float(ni.w);
    float a0 = 0, a1 = 0, a2 = 0, a3 = 0, a4 = 0, a5 = 0;
    int j = s;
    for (; j + 3 < e; j += 4) {
        int s0 = edge_src[j], s1 = edge_src[j + 1], s2 = edge_src[j + 2], s3 = edge_src[j + 3];
        const __half2* p0 = xs + s0 * 24 + lane * 3;
        const __half2* p1 = xs + s1 * 24 + lane * 3;
        const __half2* p2 = xs + s2 * 24 + lane * 3;
        const __half2* p3 = xs + s3 * 24 + lane * 3;
        __half2 v00, v01, v02, v10, v11, v12, v20, v21, v22, v30, v31, v32;
        LOAD3(p0, v00, v01, v02);
        LOAD3(p1, v10, v11, v12);
        LOAD3(p2, v20, v21, v22);
        LOAD3(p3, v30, v31, v32);
        ACC6(v00, v01, v02);
        ACC6(v10, v11, v12);
        ACC6(v20, v21, v22);
        ACC6(v30, v31, v32);
    }
    for (; j < e; ++j) {
        const __half2* p0 = xs + edge_src[j] * 24 + lane * 3;
        __half2 v00, v01, v02;
        LOAD3(p0, v00, v01, v02);
        ACC6(v00, v01, v02);
    }
    float sc = dv * dv;
    __half2* q = h1 + node * 24 + lane * 3;
    q[0] = __floats2half2_rn(a0 * sc, a1 * sc);
    q[1] = __floats2half2_rn(a2 * sc, a3 * sc);
    q[2] = __floats2half2_rn(a4 * sc, a5 * sc);
}

// ---- gather round 2 fused with GEMM ----
__global__ void gather2_gemm_kernel(const __half2* __restrict__ h1,
                                    const int* __restrict__ edge_src,
                                    const int4* __restrict__ nodeinfo,
                                    const float* __restrict__ W,
                                    const float* __restrict__ b,
                                    float* __restrict__ out) {
    __shared__ float sW[IN_CH * OUT_CH];
    __shared__ float sb[OUT_CH];
    __shared__ float sh[32][IN_CH + 1];

    for (int i = threadIdx.x; i < IN_CH * OUT_CH; i += 256) sW[i] = W[i];
    if (threadIdx.x < OUT_CH) sb[threadIdx.x] = b[threadIdx.x];

    int nl = threadIdx.x >> 3;
    int lane = threadIdx.x & 7;
    int g = blockIdx.x * 32 + nl;
    int4 ni = nodeinfo[g];
    int node = ni.x, s = ni.y, e = ni.y + ni.z;
    float dv = __int_as_float(ni.w);

    float a0 = 0, a1 = 0, a2 = 0, a3 = 0, a4 = 0, a5 = 0;
    int j = s;
    for (; j + 3 < e; j += 4) {
        int s0 = edge_src[j], s1 = edge_src[j + 1], s2 = edge_src[j + 2], s3 = edge_src[j + 3];
        const __half2* p0 = h1 + s0 * 24 + lane * 3;
        const __half2* p1 = h1 + s1 * 24 + lane * 3;
        const __half2* p2 = h1 + s2 * 24 + lane * 3;
        const __half2* p3 = h1 + s3 * 24 + lane * 3;
        __half2 v00, v01, v02, v10, v11, v12, v20, v21, v22, v30, v31, v32;
        LOAD3(p0, v00, v01, v02);
        LOAD3(p1, v10, v11, v12);
        LOAD3(p2, v20, v21, v22);
        LOAD3(p3, v30, v31, v32);
        ACC6(v00, v01, v02);
        ACC6(v10, v11, v12);
        ACC6(v20, v21, v22);
        ACC6(v30, v31, v32);
    }
    for (; j < e; ++j) {
        const __half2* p0 = h1 + edge_src[j] * 24 + lane * 3;
        __half2 v00, v01, v02;
        LOAD3(p0, v00, v01, v02);
        ACC6(v00, v01, v02);
    }
    int c0 = 6 * lane;
    sh[nl][c0 + 0] = a0 * dv;
    sh[nl][c0 + 1] = a1 * dv;
    sh[nl][c0 + 2] = a2 * dv;
    sh[nl][c0 + 3] = a3 * dv;
    sh[nl][c0 + 4] = a4 * dv;
    sh[nl][c0 + 5] = a5 * dv;
    __syncthreads();

    int j0 = lane * 8;
    float acc[8];
    #pragma unroll
    for (int i = 0; i < 8; i++) acc[i] = sb[j0 + i];
    for (int k = 0; k < IN_CH; k++) {
        float s0 = sh[nl][k];
        #pragma unroll
        for (int i = 0; i < 8; i++) acc[i] += s0 * sW[k * OUT_CH + j0 + i];
    }
    float4* o = (float4*)(out + (size_t)node * OUT_CH + j0);
    o[0] = make_float4(acc[0], acc[1], acc[2], acc[3]);
    o[1] = make_float4(acc[4], acc[5], acc[6], acc[7]);
}

extern "C" void kernel_launch(void* const* d_in, const int* in_sizes, int n_in,
                              void* d_out, int out_size, void* d_ws, size_t ws_size,
                              hipStream_t stream) {
    const float* x   = (const float*)d_in[0];
    const int*   ei  = (const int*)d_in[1];
    const float* W   = (const float*)d_in[2];
    const float* b   = (const float*)d_in[3];
    float* out = (float*)d_out;

    const int* row = ei;             // edge_index[0] (sources)
    const int* col = ei + N_EDGES;   // edge_index[1] (destinations)

    // ws layout (int offsets), ~28.4 MB total. xs aliases bucketed (dead
    // after fine_sort) and extends past it.
    int* ws_i = (int*)d_ws;
    int* bucketCount  = ws_i;                  // [1024]
    int* binTotal     = ws_i + 1024;           // [64]
    int* binCursor    = ws_i + 1088;           // [64] (overwritten by binscan)
    int* bucketStart  = ws_i + 1152;           // [1025]
    int* bucketCursor = ws_i + 2304;           // [1024]
    int* deg          = ws_i + 3584;           // [100352]
    int* start        = ws_i + 103936;         // [100352]
    float* dis        = (float*)(ws_i + 204288);   // [100352]
    int4* nodeinfo    = (int4*)(ws_i + 304640);    // [100352] int4 (16B-aligned)
    int* edge_src     = ws_i + 706048;         // [1600000]
    int* bucketed     = ws_i + 2306048;        // [1600000] packed edges
    __half2* xs       = (__half2*)(ws_i + 2306048); // [2400000] half2, aliases bucketed
    __half2* h1       = (__half2*)(ws_i + 4706048); // [2400000] half2

    hipMemsetAsync(bucketCount, 0, 1088 * sizeof(int), stream);  // bucketCount + binTotal

    bucket_hist_kernel<<<NBLK_EDGE, 256, 0, stream>>>(col, bucketCount);
    bucket_scan_kernel<<<1, 256, 0, stream>>>(bucketCount, bucketStart, bucketCursor);
    bucket_scatter_kernel<<<NBLK_EDGE, 256, 0, stream>>>(row, col, bucketCursor, bucketed);
    fine_sort_kernel<<<(N_NODES + 127) / 128, 256, 0, stream>>>(bucketed, bucketStart,
                                                                edge_src, deg, start, dis, binTotal);
    binscan_kernel<<<1, 64, 0, stream>>>(binTotal, binCursor);
    order_kernel<<<(N_NODES + 255) / 256, 256, 0, stream>>>(deg, start, dis, binCursor,
                                                            nodeinfo, N_NODES);
    prescale_kernel<<<(N_NODES * 24 + 255) / 256, 256, 0, stream>>>(x, dis, xs, N_NODES * 24);

    // 32 nodes per 256-thread block; 100000/32 = 3125 exactly
    gather1_kernel<<<N_NODES / 32, 256, 0, stream>>>(xs, edge_src, nodeinfo, h1);
    gather2_gemm_kernel<<<N_NODES / 32, 256, 0, stream>>>(h1, edge_src, nodeinfo, W, b, out);
}